// Round 11
// baseline (1503.664 us; speedup 1.0000x reference)
//
#include <hip/hip_runtime.h>
#include <math.h>

#define NL 16
#define R1 513                       // (RMAX+1)
#define LVL_STRIDE (R1 * R1 * 2)     // floats per level
#define HID 128
#define IN_DIM 32
#define NWAVES 8                     // 512-thread block: 8 waves share one weight copy

typedef float f32x4 __attribute__((ext_vector_type(4)));
typedef short s16x8 __attribute__((ext_vector_type(8)));   // 8 bf16 (4 VGPRs)

struct ResArg { int r[NL]; };

static __device__ __forceinline__ unsigned short f2h(float f) {
    __bf16 b = (__bf16)f;                       // RNE f32->bf16
    return __builtin_bit_cast(unsigned short, b);
}
static __device__ __forceinline__ float4 ld16(const float* p) {
    float4 q;                                   // 16B load, 8B-aligned address
    __builtin_memcpy(&q, (const float*)__builtin_assume_aligned((const void*)p, 8), 16);
    return q;
}

// ROUND-5 LESSON: VGPR_Count=128 reported but occupancy stuck at 22% -> the
// unified VGPR+AGPR total was ~256 (MT=4 kept acc1[128f]+acc2[128f] live).
// MT=1 cuts peak live regs to ~100 total, so (512,4) [cap 128/wave] is now
// SAFE (round-3's spill came from forcing 128 onto a ~256-reg structure)
// and guarantees 2 blocks/CU = 16 waves/CU.
__global__ __launch_bounds__(512, 4)
void ngp_mfma(const float* __restrict__ x,
              const float* __restrict__ grids,
              const float* __restrict__ W1, const float* __restrict__ b1,
              const float* __restrict__ W2, const float* __restrict__ b2,
              const float* __restrict__ W3, const float* __restrict__ b3,
              float* __restrict__ out, int n_pts, ResArg res)
{
    // LDS: W1^T 8KB + W2^T 32KB + misc 1.6KB + 8 per-wave h1 tiles 32KB = 73.6KB -> 2 blocks/CU
    __shared__ unsigned short w1t[IN_DIM * HID];      // [n=128][k=32] bf16, swizzled
    __shared__ unsigned short w2t[HID * HID];         // [n=128][k=128] bf16, swizzled
    __shared__ float b1s[HID], b2s[HID], w3s[HID];
    __shared__ int rs[NL];
    __shared__ unsigned short h1t[NWAVES][16 * HID];  // per-wave transpose tile (swizzled)

    const int tid = threadIdx.x;

    // ---- setup: stage weights (transposed, bf16, XOR-swizzled) ----
    for (int idx = tid; idx < IN_DIM * HID; idx += 512) {
        int n = idx & 127, k = idx >> 7;              // W1 global is [k][n], read coalesced
        w1t[(n * IN_DIM + k) ^ ((n & 7) << 3)] = f2h(W1[idx]);
    }
    for (int idx = tid; idx < HID * HID; idx += 512) {
        int n = idx & 127, k = idx >> 7;              // W2 global is [k][n]
        w2t[(n * HID + k) ^ ((n & 7) << 3)] = f2h(W2[idx]);
    }
    if (tid < HID) { b1s[tid] = b1[tid]; b2s[tid] = b2[tid]; w3s[tid] = W3[tid]; }
    if (tid == 0) {
        #pragma unroll
        for (int l = 0; l < NL; ++l) rs[l] = res.r[l];   // static kernarg indices only
    }
    __syncthreads();

    const int lane = tid & 63;
    const int wv   = tid >> 6;
    const int g    = lane >> 4;      // k-slice group (also level group 4g..4g+3)
    const int cl   = lane & 15;      // row/col lane id
    unsigned short* myh1 = h1t[wv];

    // per-lane level tables (levels 4g..4g+3), hoisted out of the main loop
    int lr[4]; float lrf[4]; const float* gp[4];
    #pragma unroll
    for (int lv = 0; lv < 4; ++lv) {
        int L = 4 * g + lv;
        lr[lv]  = rs[L];
        lrf[lv] = (float)lr[lv];
        gp[lv]  = grids + (size_t)L * LVL_STRIDE;
    }

    const int gw = blockIdx.x * NWAVES + wv;
    const int nw = gridDim.x * NWAVES;
    const float bias3 = b3[0];

    for (int base = gw * 16; base < n_pts; base += nw * 16) {

        // ---- multires bilinear gather -> layer-1 A-fragment (in-register) ----
        s16x8 fa;
        {
            int pt = min(base + cl, n_pts - 1);
            float2 xv = *(const float2*)(x + 2 * pt);
            #pragma unroll
            for (int lv = 0; lv < 4; ++lv) {
                int   r  = lr[lv];
                float px = xv.x * lrf[lv], py = xv.y * lrf[lv];
                float fx = floorf(px), fy = floorf(py);
                int ix0 = (int)fx; ix0 = max(0, min(ix0, r));
                int iy0 = (int)fy; iy0 = max(0, min(iy0, r));
                int ix1 = min(ix0 + 1, r);
                float wx = px - fx, wy = py - fy;
                float omx = 1.f - wx, omy = 1.f - wy;
                int iyl = min(iy0, r - 1);            // 16B load covers (iyl, iyl+1)
                float4 q0 = ld16(gp[lv] + (size_t)(ix0 * R1 + iyl) * 2);
                float4 q1 = ld16(gp[lv] + (size_t)(ix1 * R1 + iyl) * 2);
                bool hi = (iy0 != iyl);               // only when iy0 == r
                float f00x = hi ? q0.z : q0.x, f00y = hi ? q0.w : q0.y;
                float f10x = hi ? q1.z : q1.x, f10y = hi ? q1.w : q1.y;
                float f01x = q0.z, f01y = q0.w;
                float f11x = q1.z, f11y = q1.w;
                float vx = (f00x * omx + f10x * wx) * omy + (f01x * omx + f11x * wx) * wy;
                float vy = (f00y * omx + f10y * wx) * omy + (f01y * omx + f11y * wx) * wy;
                fa[2 * lv + 0] = (short)f2h(vx);      // k = 8g + 2*lv + f
                fa[2 * lv + 1] = (short)f2h(vy);
            }
        }

        // ---- layer 1: D[pt][neuron] = feats @ W1 + b1 (K=32, one MFMA step) ----
        f32x4 acc1[8];
        #pragma unroll
        for (int t = 0; t < 8; ++t) {
            int n = t * 16 + cl;
            float bb = b1s[n];
            s16x8 w1f = *(const s16x8*)&w1t[(n * IN_DIM + 8 * g) ^ ((n & 7) << 3)];
            f32x4 c = {bb, bb, bb, bb};
            acc1[t] = __builtin_amdgcn_mfma_f32_16x16x32_bf16(fa, w1f, c, 0, 0, 0);
        }

        // ---- relu -> bf16 -> per-wave LDS transpose -> layer-2 A-frags ----
        s16x8 ha[4];
        #pragma unroll
        for (int t = 0; t < 8; ++t) {
            int col = t * 16 + cl;
            f32x4 v = acc1[t];
            #pragma unroll
            for (int j = 0; j < 4; ++j) {
                int row = 4 * g + j;                  // D row = point-in-tile
                myh1[(row * HID + col) ^ ((row & 7) << 3)] = f2h(fmaxf(v[j], 0.f));
            }
        }
        #pragma unroll
        for (int s = 0; s < 4; ++s)                   // A-frag: row=cl, k=32s+8g..+7
            ha[s] = *(const s16x8*)&myh1[(cl * HID + s * 32 + 8 * g) ^ ((cl & 7) << 3)];

        // ---- layer 2: K=128 in 4 MFMA steps ----
        f32x4 acc2[8];
        #pragma unroll
        for (int t = 0; t < 8; ++t) {
            float bb = b2s[t * 16 + cl];
            f32x4 c = {bb, bb, bb, bb};
            acc2[t] = c;
        }
        #pragma unroll
        for (int s = 0; s < 4; ++s) {
            #pragma unroll
            for (int t = 0; t < 8; ++t) {
                int n = t * 16 + cl;
                s16x8 w2f = *(const s16x8*)&w2t[(n * HID + s * 32 + 8 * g) ^ ((n & 7) << 3)];
                acc2[t] = __builtin_amdgcn_mfma_f32_16x16x32_bf16(ha[s], w2f, acc2[t], 0, 0, 0);
            }
        }

        // ---- layer 3 (+ relu) fused epilogue: per-lane partials, 16-lane reduce ----
        {
            float o0 = 0.f, o1 = 0.f, o2 = 0.f, o3 = 0.f;
            #pragma unroll
            for (int t = 0; t < 8; ++t) {
                float w3v = w3s[t * 16 + cl];
                f32x4 v = acc2[t];
                o0 += fmaxf(v.x, 0.f) * w3v;
                o1 += fmaxf(v.y, 0.f) * w3v;
                o2 += fmaxf(v.z, 0.f) * w3v;
                o3 += fmaxf(v.w, 0.f) * w3v;
            }
            #pragma unroll
            for (int mask = 1; mask < 16; mask <<= 1) {
                o0 += __shfl_xor(o0, mask);
                o1 += __shfl_xor(o1, mask);
                o2 += __shfl_xor(o2, mask);
                o3 += __shfl_xor(o3, mask);
            }
            if (cl < 4) {
                int row = base + 4 * g + cl;
                float val = (cl == 0) ? o0 : (cl == 1) ? o1 : (cl == 2) ? o2 : o3;
                if (row < n_pts) out[row] = val + bias3;
            }
        }
    }
}

extern "C" void kernel_launch(void* const* d_in, const int* in_sizes, int n_in,
                              void* d_out, int out_size, void* d_ws, size_t ws_size,
                              hipStream_t stream)
{
    const float* x     = (const float*)d_in[0];
    const float* grids = (const float*)d_in[1];
    const float* W1    = (const float*)d_in[2];
    const float* b1    = (const float*)d_in[3];
    const float* W2    = (const float*)d_in[4];
    const float* b2    = (const float*)d_in[5];
    const float* W3    = (const float*)d_in[6];
    const float* b3    = (const float*)d_in[7];
    float* outp        = (float*)d_out;

    int n_pts = in_sizes[0] / 2;

    ResArg res;
    double growth = pow(512.0 / 16.0, 1.0 / 15.0);
    for (int l = 0; l < NL; ++l)
        res.r[l] = (int)floor(16.0 * pow(growth, (double)l));

    dim3 block(512);
    dim3 grid(512);   // 512 blocks x 2/CU resident on 256 CUs; grid-stride loop (32 iters/wave)
    hipLaunchKernelGGL(ngp_mfma, grid, block, 0, stream,
                       x, grids, W1, b1, W2, b2, W3, b3, outp, n_pts, res);
}

// Round 13
// 987.152 us; speedup vs baseline: 1.5232x; 1.5232x over previous
//
#include <hip/hip_runtime.h>
#include <math.h>

#define NL 16
#define R1 513                       // (RMAX+1) allocated leading dim of input grids
#define LVL_STRIDE (R1 * R1 * 2)     // floats per level
#define HID 128
#define IN_DIM 32
#define NWAVES 8                     // 512-thread block: 8 waves share one weight copy

typedef float f32x4 __attribute__((ext_vector_type(4)));
typedef short s16x8 __attribute__((ext_vector_type(8)));   // 8 bf16 / 8 u16 (4 VGPRs)

struct LvlArg { int r[NL]; int start[NL]; };   // start = quad-record offset of level l

static __device__ __forceinline__ unsigned short f2h(float f) {
    __bf16 b = (__bf16)f;                       // RNE f32->bf16
    return __builtin_bit_cast(unsigned short, b);
}
static __device__ __forceinline__ float b2f(short u) {
    return __builtin_bit_cast(float, (unsigned)((unsigned short)u) << 16);
}

// ---------------------------------------------------------------------------
// Pass 1: quad-pack the grids. One 16B record per (level, ix, iy):
//   [f00x f00y f10x f10y f01x f01y f11x f11y] in bf16, clamping baked in.
// Halves the main kernel's scattered line-fills (32 -> 16 per point), which
// is the R11 bottleneck model (L1 MSHR x fill-latency throughput).
// blockIdx.y = level (wave-uniform kernarg indexing -> no scratch).
// ---------------------------------------------------------------------------
__global__ __launch_bounds__(256)
void build_quads(const float* __restrict__ grids, unsigned short* __restrict__ q,
                 LvlArg la)
{
    const int l = blockIdx.y;
    const int r = la.r[l];
    const int w = r + 1;
    const int cells = w * w;
    const float2* g  = (const float2*)(grids + (size_t)l * LVL_STRIDE);
    unsigned short* qb = q + (size_t)la.start[l] * 8;

    for (int c = blockIdx.x * 256 + threadIdx.x; c < cells; c += gridDim.x * 256) {
        int ix = c / w, iy = c - ix * w;
        int ix1 = min(ix + 1, r), iy1 = min(iy + 1, r);
        float2 f00 = g[ix  * R1 + iy ];
        float2 f01 = g[ix  * R1 + iy1];
        float2 f10 = g[ix1 * R1 + iy ];
        float2 f11 = g[ix1 * R1 + iy1];
        s16x8 o;
        o[0] = (short)f2h(f00.x); o[1] = (short)f2h(f00.y);
        o[2] = (short)f2h(f10.x); o[3] = (short)f2h(f10.y);
        o[4] = (short)f2h(f01.x); o[5] = (short)f2h(f01.y);
        o[6] = (short)f2h(f11.x); o[7] = (short)f2h(f11.y);
        *(s16x8*)(qb + (size_t)c * 8) = o;        // aligned 16B store
    }
}

// ---------------------------------------------------------------------------
// Pass 2: fused encode + MLP. Round-5 shape (MT=1, 8 waves sharing weights,
// (512,2): VGPR=128 + AGPRs, no spill, ~8 waves/CU). Occupancy is register-
// capped (R11 lesson) — the win here is 1 quad load per level per point.
// ---------------------------------------------------------------------------
__global__ __launch_bounds__(512, 2)
void ngp_mfma(const float* __restrict__ x,
              const unsigned short* __restrict__ q,
              const float* __restrict__ W1, const float* __restrict__ b1,
              const float* __restrict__ W2, const float* __restrict__ b2,
              const float* __restrict__ W3, const float* __restrict__ b3,
              float* __restrict__ out, int n_pts, LvlArg la)
{
    // LDS: W1^T 8KB + W2^T 32KB + misc ~1.7KB + 8 per-wave h1 tiles 32KB = ~73.7KB
    __shared__ unsigned short w1t[IN_DIM * HID];      // [n=128][k=32] bf16, swizzled
    __shared__ unsigned short w2t[HID * HID];         // [n=128][k=128] bf16, swizzled
    __shared__ float b1s[HID], b2s[HID], w3s[HID];
    __shared__ int rs_s[NL], st_s[NL];
    __shared__ unsigned short h1t[NWAVES][16 * HID];  // per-wave transpose tile (swizzled)

    const int tid = threadIdx.x;

    // ---- setup: stage weights (transposed, bf16, XOR-swizzled) ----
    for (int idx = tid; idx < IN_DIM * HID; idx += 512) {
        int n = idx & 127, k = idx >> 7;              // W1 global is [k][n], read coalesced
        w1t[(n * IN_DIM + k) ^ ((n & 7) << 3)] = f2h(W1[idx]);
    }
    for (int idx = tid; idx < HID * HID; idx += 512) {
        int n = idx & 127, k = idx >> 7;              // W2 global is [k][n]
        w2t[(n * HID + k) ^ ((n & 7) << 3)] = f2h(W2[idx]);
    }
    if (tid < HID) { b1s[tid] = b1[tid]; b2s[tid] = b2[tid]; w3s[tid] = W3[tid]; }
    if (tid == 0) {
        #pragma unroll
        for (int l = 0; l < NL; ++l) { rs_s[l] = la.r[l]; st_s[l] = la.start[l]; }
    }
    __syncthreads();

    const int lane = tid & 63;
    const int wv   = tid >> 6;
    const int g    = lane >> 4;      // k-slice group (also level group 4g..4g+3)
    const int cl   = lane & 15;      // row/col lane id
    unsigned short* myh1 = h1t[wv];

    // per-lane level tables (levels 4g..4g+3), hoisted; dynamic index via LDS only
    int lr[4], lw[4]; float lrf[4]; const unsigned short* qp[4];
    #pragma unroll
    for (int lv = 0; lv < 4; ++lv) {
        int L  = 4 * g + lv;
        int r  = rs_s[L];
        lr[lv] = r; lw[lv] = r + 1; lrf[lv] = (float)r;
        qp[lv] = q + (size_t)st_s[L] * 8;
    }

    const int gw = blockIdx.x * NWAVES + wv;
    const int nw = gridDim.x * NWAVES;
    const float bias3 = b3[0];

    for (int base = gw * 16; base < n_pts; base += nw * 16) {

        // ---- gather: ONE 16B quad load per level -> layer-1 A-fragment ----
        s16x8 fa;
        {
            int pt = min(base + cl, n_pts - 1);
            float2 xv = *(const float2*)(x + 2 * pt);
            #pragma unroll
            for (int lv = 0; lv < 4; ++lv) {
                float px = xv.x * lrf[lv], py = xv.y * lrf[lv];
                float fx = floorf(px), fy = floorf(py);
                int ix = (int)fx; ix = max(0, min(ix, lr[lv]));
                int iy = (int)fy; iy = max(0, min(iy, lr[lv]));
                float wx = px - fx, wy = py - fy;
                float omx = 1.f - wx, omy = 1.f - wy;
                s16x8 quad = *(const s16x8*)(qp[lv] + (size_t)(ix * lw[lv] + iy) * 8);
                float f00x = b2f(quad[0]), f00y = b2f(quad[1]);
                float f10x = b2f(quad[2]), f10y = b2f(quad[3]);
                float f01x = b2f(quad[4]), f01y = b2f(quad[5]);
                float f11x = b2f(quad[6]), f11y = b2f(quad[7]);
                float vx = (f00x * omx + f10x * wx) * omy + (f01x * omx + f11x * wx) * wy;
                float vy = (f00y * omx + f10y * wx) * omy + (f01y * omx + f11y * wx) * wy;
                fa[2 * lv + 0] = (short)f2h(vx);      // k = 8g + 2*lv + f
                fa[2 * lv + 1] = (short)f2h(vy);
            }
        }

        // ---- layer 1: D[pt][neuron] = feats @ W1 + b1 (K=32, one MFMA step) ----
        f32x4 acc1[8];
        #pragma unroll
        for (int t = 0; t < 8; ++t) {
            int n = t * 16 + cl;
            float bb = b1s[n];
            s16x8 w1f = *(const s16x8*)&w1t[(n * IN_DIM + 8 * g) ^ ((n & 7) << 3)];
            f32x4 c = {bb, bb, bb, bb};
            acc1[t] = __builtin_amdgcn_mfma_f32_16x16x32_bf16(fa, w1f, c, 0, 0, 0);
        }

        // ---- relu -> bf16 -> per-wave LDS transpose -> layer-2 A-frags ----
        s16x8 ha[4];
        #pragma unroll
        for (int t = 0; t < 8; ++t) {
            int col = t * 16 + cl;
            f32x4 v = acc1[t];
            #pragma unroll
            for (int j = 0; j < 4; ++j) {
                int row = 4 * g + j;                  // D row = point-in-tile
                myh1[(row * HID + col) ^ ((row & 7) << 3)] = f2h(fmaxf(v[j], 0.f));
            }
        }
        #pragma unroll
        for (int s = 0; s < 4; ++s)                   // A-frag: row=cl, k=32s+8g..+7
            ha[s] = *(const s16x8*)&myh1[(cl * HID + s * 32 + 8 * g) ^ ((cl & 7) << 3)];

        // ---- layer 2: K=128 in 4 MFMA steps ----
        f32x4 acc2[8];
        #pragma unroll
        for (int t = 0; t < 8; ++t) {
            float bb = b2s[t * 16 + cl];
            f32x4 c = {bb, bb, bb, bb};
            acc2[t] = c;
        }
        #pragma unroll
        for (int s = 0; s < 4; ++s) {
            #pragma unroll
            for (int t = 0; t < 8; ++t) {
                int n = t * 16 + cl;
                s16x8 w2f = *(const s16x8*)&w2t[(n * HID + s * 32 + 8 * g) ^ ((n & 7) << 3)];
                acc2[t] = __builtin_amdgcn_mfma_f32_16x16x32_bf16(ha[s], w2f, acc2[t], 0, 0, 0);
            }
        }

        // ---- layer 3 (+ relu) fused epilogue: per-lane partials, 16-lane reduce ----
        {
            float o0 = 0.f, o1 = 0.f, o2 = 0.f, o3 = 0.f;
            #pragma unroll
            for (int t = 0; t < 8; ++t) {
                float w3v = w3s[t * 16 + cl];
                f32x4 v = acc2[t];
                o0 += fmaxf(v.x, 0.f) * w3v;
                o1 += fmaxf(v.y, 0.f) * w3v;
                o2 += fmaxf(v.z, 0.f) * w3v;
                o3 += fmaxf(v.w, 0.f) * w3v;
            }
            #pragma unroll
            for (int mask = 1; mask < 16; mask <<= 1) {
                o0 += __shfl_xor(o0, mask);
                o1 += __shfl_xor(o1, mask);
                o2 += __shfl_xor(o2, mask);
                o3 += __shfl_xor(o3, mask);
            }
            if (cl < 4) {
                int row = base + 4 * g + cl;
                float val = (cl == 0) ? o0 : (cl == 1) ? o1 : (cl == 2) ? o2 : o3;
                if (row < n_pts) out[row] = val + bias3;
            }
        }
    }
}

extern "C" void kernel_launch(void* const* d_in, const int* in_sizes, int n_in,
                              void* d_out, int out_size, void* d_ws, size_t ws_size,
                              hipStream_t stream)
{
    const float* x     = (const float*)d_in[0];
    const float* grids = (const float*)d_in[1];
    const float* W1    = (const float*)d_in[2];
    const float* b1    = (const float*)d_in[3];
    const float* W2    = (const float*)d_in[4];
    const float* b2    = (const float*)d_in[5];
    const float* W3    = (const float*)d_in[6];
    const float* b3    = (const float*)d_in[7];
    float* outp        = (float*)d_out;

    int n_pts = in_sizes[0] / 2;

    // RES = floor(16 * growth**l), growth = 32**(1/15); start = cumsum((r+1)^2)
    LvlArg la;
    double growth = pow(512.0 / 16.0, 1.0 / 15.0);
    int acc = 0;
    for (int l = 0; l < NL; ++l) {
        int r = (int)floor(16.0 * pow(growth, (double)l));
        la.r[l] = r;
        la.start[l] = acc;
        acc += (r + 1) * (r + 1);
    }
    // total quad bytes = acc * 16  (~11.4 MB) lives at the front of d_ws,
    // rebuilt every launch (harness re-poisons d_ws before each timed call).
    unsigned short* qbuf = (unsigned short*)d_ws;

    build_quads<<<dim3(128, NL), 256, 0, stream>>>(grids, qbuf, la);

    dim3 block(512);
    dim3 grid(512);   // grid-stride; occupancy is register-capped at ~8 waves/CU (R11)
    hipLaunchKernelGGL(ngp_mfma, grid, block, 0, stream,
                       x, qbuf, W1, b1, W2, b2, W3, b3, outp, n_pts, la);
}